// Round 5
// baseline (311.115 us; speedup 1.0000x reference)
//
#include <hip/hip_runtime.h>
#include <hip/hip_bf16.h>
#include <math.h>

#define Bz 64
#define Sz 512
#define Hz 768
#define Nz 128
#define Ez 1024
#define GHz 128
#define FHz 256
#define Lz 2
#define BNz (Bz * Nz)          // 8192
#define CPSTRIDE (BNz * GHz)   // 1048576 floats per K-chunk partial

// ============ node gather: per (b,n) block; wave-synchronous gate, no in-loop barriers ============
// nf[b*N+n][:] = (sum_{s: submap[b,s]==n} sigmoid(lh[b,s].wr + br) * lh[b,s]) / max(cnt,1)
// 128 threads = 2 waves; each wave processes alternate list entries; lane owns 12 contiguous floats.
__global__ void k_node_gather(const float* __restrict__ lh, const int* __restrict__ submap,
                              const float* __restrict__ wr, const float* __restrict__ br,
                              float* __restrict__ nf) {
    int n = blockIdx.x, b = blockIdx.y;
    int t = threadIdx.x;                  // 128
    int lane = t & 63, wid = t >> 6;
    __shared__ int list[Sz];
    __shared__ int lcnt;
    __shared__ float partial[Hz];
    if (t == 0) lcnt = 0;
    __syncthreads();
    #pragma unroll
    for (int j = 0; j < 4; ++j) {
        int s = t + 128 * j;
        if (submap[b * Sz + s] == n) { int p = atomicAdd(&lcnt, 1); list[p] = s; }
    }
    __syncthreads();
    int cnt = lcnt;
    float brv = br[0];
    const float* wp = wr + lane * 12;
    float4 w0 = *(const float4*)&wp[0];
    float4 w1 = *(const float4*)&wp[4];
    float4 w2 = *(const float4*)&wp[8];
    float4 a0 = {0,0,0,0}, a1 = {0,0,0,0}, a2 = {0,0,0,0};
    for (int i = wid; i < cnt; i += 2) {
        const float* x = lh + (size_t)(b * Sz + list[i]) * Hz + lane * 12;
        float4 v0 = *(const float4*)&x[0];
        float4 v1 = *(const float4*)&x[4];
        float4 v2 = *(const float4*)&x[8];
        float p = v0.x*w0.x + v0.y*w0.y + v0.z*w0.z + v0.w*w0.w
                + v1.x*w1.x + v1.y*w1.y + v1.z*w1.z + v1.w*w1.w
                + v2.x*w2.x + v2.y*w2.y + v2.z*w2.z + v2.w*w2.w;
        #pragma unroll
        for (int off = 32; off > 0; off >>= 1) p += __shfl_down(p, off);
        float z = __shfl(p, 0) + brv;
        float g = 1.0f / (1.0f + __expf(-z));
        a0.x += g*v0.x; a0.y += g*v0.y; a0.z += g*v0.z; a0.w += g*v0.w;
        a1.x += g*v1.x; a1.y += g*v1.y; a1.z += g*v1.z; a1.w += g*v1.w;
        a2.x += g*v2.x; a2.y += g*v2.y; a2.z += g*v2.z; a2.w += g*v2.w;
    }
    if (wid == 1) {
        float* pp = partial + lane * 12;
        *(float4*)&pp[0] = a0; *(float4*)&pp[4] = a1; *(float4*)&pp[8] = a2;
    }
    __syncthreads();
    if (wid == 0) {
        float invc = 1.0f / fmaxf((float)cnt, 1.0f);
        const float* pp = partial + lane * 12;
        float4 p0 = *(const float4*)&pp[0];
        float4 p1 = *(const float4*)&pp[4];
        float4 p2 = *(const float4*)&pp[8];
        float* o = nf + (size_t)(b * Nz + n) * Hz + lane * 12;
        *(float4*)&o[0] = make_float4((a0.x+p0.x)*invc, (a0.y+p0.y)*invc, (a0.z+p0.z)*invc, (a0.w+p0.w)*invc);
        *(float4*)&o[4] = make_float4((a1.x+p1.x)*invc, (a1.y+p1.y)*invc, (a1.z+p1.z)*invc, (a1.w+p1.w)*invc);
        *(float4*)&o[8] = make_float4((a2.x+p2.x)*invc, (a2.y+p2.y)*invc, (a2.z+p2.z)*invc, (a2.w+p2.w)*invc);
    }
}

// ============ GEMM: Cp[chunk] = A(BN x K[slice]) @ W(K x 128) ============
// 128x128 tile, 8x8 per thread, BK=32, A stored k-major in LDS -> all-b128 inner loop.
template <int K, int KC>
__global__ void k_gemm(const float* __restrict__ A, const float* __restrict__ W,
                       float* __restrict__ Cp) {
    __shared__ __align__(16) float At[32 * 128];   // [k][row]
    __shared__ __align__(16) float Ws[32 * 128];   // [k][col]
    int block_row = blockIdx.x * 128;
    int k_base = blockIdx.y * KC;
    int tid = threadIdx.x;                // 256
    int tx = tid & 15;                    // cols tx*8 .. +7
    int ty = tid >> 4;                    // rows ty*8 .. +7
    float acc[8][8];
    #pragma unroll
    for (int r = 0; r < 8; ++r)
        #pragma unroll
        for (int c = 0; c < 8; ++c) acc[r][c] = 0.0f;

    for (int kk = 0; kk < KC; kk += 32) {
        int k0 = k_base + kk;
        // A tile: 128 rows x 32 k = 1024 float4, transposed into At[k][row]
        #pragma unroll
        for (int j = 0; j < 4; ++j) {
            int idx = tid + 256 * j;
            int r = idx >> 3, c4 = idx & 7;          // r 0..127, c4 0..7 (k = c4*4..+3)
            float4 v = *(const float4*)&A[(size_t)(block_row + r) * K + k0 + c4 * 4];
            At[(c4 * 4 + 0) * 128 + r] = v.x;
            At[(c4 * 4 + 1) * 128 + r] = v.y;
            At[(c4 * 4 + 2) * 128 + r] = v.z;
            At[(c4 * 4 + 3) * 128 + r] = v.w;
        }
        // W tile: 32 k x 128 cols = 1024 float4
        #pragma unroll
        for (int j = 0; j < 4; ++j) {
            int idx = tid + 256 * j;
            int r = idx >> 5, c4 = idx & 31;
            *(float4*)&Ws[r * 128 + c4 * 4] = *(const float4*)&W[(size_t)(k0 + r) * 128 + c4 * 4];
        }
        __syncthreads();
        #pragma unroll 8
        for (int k = 0; k < 32; ++k) {
            float4 a0 = *(const float4*)&At[k * 128 + ty * 8];
            float4 a1 = *(const float4*)&At[k * 128 + ty * 8 + 4];
            float4 w0 = *(const float4*)&Ws[k * 128 + tx * 8];
            float4 w1 = *(const float4*)&Ws[k * 128 + tx * 8 + 4];
            float a[8] = {a0.x, a0.y, a0.z, a0.w, a1.x, a1.y, a1.z, a1.w};
            float w[8] = {w0.x, w0.y, w0.z, w0.w, w1.x, w1.y, w1.z, w1.w};
            #pragma unroll
            for (int r = 0; r < 8; ++r)
                #pragma unroll
                for (int c = 0; c < 8; ++c) acc[r][c] += a[r] * w[c];
        }
        __syncthreads();
    }
    float* Cb = Cp + (size_t)blockIdx.y * CPSTRIDE;
    #pragma unroll
    for (int r = 0; r < 8; ++r) {
        size_t o = (size_t)(block_row + ty * 8 + r) * 128 + tx * 8;
        *(float4*)&Cb[o]     = make_float4(acc[r][0], acc[r][1], acc[r][2], acc[r][3]);
        *(float4*)&Cb[o + 4] = make_float4(acc[r][4], acc[r][5], acc[r][6], acc[r][7]);
    }
}

// ============ reduce K-chunk partials: h = sum_c Cp[c] ============
template <int NCH>
__global__ void k_reduce(const float* __restrict__ Cp, float* __restrict__ h) {
    size_t i = ((size_t)blockIdx.x * 256 + threadIdx.x) * 4;
    float4 s = *(const float4*)&Cp[i];
    #pragma unroll
    for (int c = 1; c < NCH; ++c) {
        float4 v = *(const float4*)&Cp[(size_t)c * CPSTRIDE + i];
        s.x += v.x; s.y += v.y; s.z += v.z; s.w += v.w;
    }
    *(float4*)&h[i] = s;
}

// ============ edge gather per (b,dst), fused degree histogram + bias + relu ============
// 256 threads: col = t&127, half = t>>7 processes alternate matched edges.
__global__ void k_edge_gather(const float* __restrict__ h, const int* __restrict__ ei,
                              const float* __restrict__ bias, float* __restrict__ out) {
    int d = blockIdx.x, b = blockIdx.y;
    int t = threadIdx.x;                  // 256
    __shared__ int list[Ez];
    __shared__ int lcnt;
    __shared__ int hist[Nz];
    __shared__ float accb[128];
    if (t == 0) lcnt = 0;
    if (t < Nz) hist[t] = 0;
    __syncthreads();
    const int* srcp = ei + b * 2 * Ez;
    const int* dstp = srcp + Ez;
    #pragma unroll
    for (int j = 0; j < 4; ++j) {
        int e = t + 256 * j;
        int dv = dstp[e];
        atomicAdd(&hist[dv], 1);          // LDS histogram (degree, dst side)
        if (dv == d) { int p = atomicAdd(&lcnt, 1); list[p] = e; }
    }
    __syncthreads();
    int cnt = lcnt;
    int col = t & 127, half = t >> 7;
    float dd = rsqrtf((float)hist[d] + 1.0f);
    float acc = (half == 0) ? h[(size_t)(b * Nz + d) * GHz + col] * dd * dd : 0.0f;  // self loop
    for (int i = half; i < cnt; i += 2) {
        int s = srcp[list[i]];
        float ds_ = rsqrtf((float)hist[s] + 1.0f);
        acc += h[(size_t)(b * Nz + s) * GHz + col] * (ds_ * dd);
    }
    if (half == 1) accb[col] = acc;
    __syncthreads();
    if (half == 0)
        out[(size_t)(b * Nz + d) * GHz + col] = fmaxf(acc + accb[col] + bias[col], 0.0f);
}

// ============ fused head: pooled = mean(x2[b]); h = relu([cls,pooled]@Wf1+bf1); out = h@Wf2+bf2 ============
__global__ void k_head(const float* __restrict__ lh, const float* __restrict__ x2,
                       const float* __restrict__ Wf1, const float* __restrict__ bf1,
                       const float* __restrict__ Wf2, const float* __restrict__ bf2,
                       float* __restrict__ out) {
    int b = blockIdx.x;
    int t = threadIdx.x;                  // 256
    __shared__ float in[Hz + GHz];        // 896
    __shared__ float buf[2][128];
    __shared__ float4 red4[4][64];
    __shared__ float hvec[FHz];
    __shared__ float red[256];
    for (int i = t; i < Hz; i += 256) in[i] = lh[(size_t)b * Sz * Hz + i];   // cls = s=0 row
    int col = t & 127, half = t >> 7;
    float s = 0.0f;
    for (int r = 0; r < 64; ++r)
        s += x2[(size_t)(b * Nz + half * 64 + r) * GHz + col];
    buf[half][col] = s;
    __syncthreads();
    if (t < 128) in[Hz + t] = (buf[0][t] + buf[1][t]) * (1.0f / Nz);
    __syncthreads();
    // mlp1: 64 col-quads x 4 k-chunks of 224
    int c4 = t & 63, kc = t >> 6;
    float4 a = {0, 0, 0, 0};
    int k1 = kc * 224 + 224;
    for (int k = kc * 224; k < k1; ++k) {
        float iv = in[k];
        float4 w = *(const float4*)&Wf1[(size_t)k * FHz + c4 * 4];
        a.x += iv * w.x; a.y += iv * w.y; a.z += iv * w.z; a.w += iv * w.w;
    }
    red4[kc][c4] = a;
    __syncthreads();
    if (t < 64) {
        float4 s0 = red4[0][t], s1 = red4[1][t], s2 = red4[2][t], s3 = red4[3][t];
        float4 bb = *(const float4*)&bf1[t * 4];
        hvec[t * 4 + 0] = fmaxf(s0.x + s1.x + s2.x + s3.x + bb.x, 0.0f);
        hvec[t * 4 + 1] = fmaxf(s0.y + s1.y + s2.y + s3.y + bb.y, 0.0f);
        hvec[t * 4 + 2] = fmaxf(s0.z + s1.z + s2.z + s3.z + bb.z, 0.0f);
        hvec[t * 4 + 3] = fmaxf(s0.w + s1.w + s2.w + s3.w + bb.w, 0.0f);
    }
    __syncthreads();
    float hv = hvec[t];
    for (int l = 0; l < Lz; ++l) {
        red[t] = hv * Wf2[t * Lz + l];
        __syncthreads();
        for (int s2 = 128; s2 > 0; s2 >>= 1) {
            if (t < s2) red[t] += red[t + s2];
            __syncthreads();
        }
        if (t == 0) out[b * Lz + l] = red[0] + bf2[l];
        __syncthreads();
    }
}

extern "C" void kernel_launch(void* const* d_in, const int* in_sizes, int n_in,
                              void* d_out, int out_size, void* d_ws, size_t ws_size,
                              hipStream_t stream) {
    const float* lh     = (const float*)d_in[0];
    const int*   submap = (const int*)d_in[1];
    const int*   ei     = (const int*)d_in[2];
    const float* wr  = (const float*)d_in[4];
    const float* br  = (const float*)d_in[5];
    const float* W1  = (const float*)d_in[6];
    const float* b1  = (const float*)d_in[7];
    const float* W2  = (const float*)d_in[8];
    const float* b2  = (const float*)d_in[9];
    const float* Wf1 = (const float*)d_in[10];
    const float* bf1 = (const float*)d_in[11];
    const float* Wf2 = (const float*)d_in[12];
    const float* bf2 = (const float*)d_in[13];
    float* out = (float*)d_out;

    // ---- workspace layout (floats), no aliasing; ~76 MB (ws is ~400 MB per harness fill) ----
    float* ws = (float*)d_ws;
    float* nf = ws;                                   // 8192 x 768
    float* Cp = nf + (size_t)BNz * Hz;                // 8 x 1048576
    float* h1 = Cp + 8 * (size_t)CPSTRIDE;            // 8192 x 128
    float* x1 = h1 + CPSTRIDE;
    float* h2 = x1 + CPSTRIDE;
    float* x2 = h2 + CPSTRIDE;

    // no memsets: every buffer fully written before read; no global atomics anywhere
    k_node_gather<<<dim3(Nz, Bz), 128, 0, stream>>>(lh, submap, wr, br, nf);

    // GCN layer 1: K=768, 8 chunks of 96 -> 512 blocks (2/CU)
    k_gemm<Hz, 96><<<dim3(BNz / 128, 8), 256, 0, stream>>>(nf, W1, Cp);
    k_reduce<8><<<CPSTRIDE / 1024, 256, 0, stream>>>(Cp, h1);
    k_edge_gather<<<dim3(Nz, Bz), 256, 0, stream>>>(h1, ei, b1, x1);

    // GCN layer 2: K=128, 4 chunks of 32 -> 256 blocks
    k_gemm<GHz, 32><<<dim3(BNz / 128, 4), 256, 0, stream>>>(x1, W2, Cp);
    k_reduce<4><<<CPSTRIDE / 1024, 256, 0, stream>>>(Cp, h2);
    k_edge_gather<<<dim3(Nz, Bz), 256, 0, stream>>>(h2, ei, b2, x2);

    k_head<<<Bz, 256, 0, stream>>>(lh, x2, Wf1, bf1, Wf2, bf2, out);
}

// Round 6
// 284.190 us; speedup vs baseline: 1.0947x; 1.0947x over previous
//
#include <hip/hip_runtime.h>
#include <hip/hip_bf16.h>
#include <math.h>

#define Bz 64
#define Sz 512
#define Hz 768
#define Nz 128
#define Ez 1024
#define GHz 128
#define FHz 256
#define Lz 2
#define BNz (Bz * Nz)          // 8192

typedef short bf16x8 __attribute__((ext_vector_type(8)));
typedef float f32x4  __attribute__((ext_vector_type(4)));
typedef unsigned short ushort;

__device__ inline ushort f2b(float f) {          // f32 -> bf16 bits, round-to-nearest-even
    union { float f; unsigned u; } v; v.f = f;
    unsigned r = (v.u + 0x7FFFu + ((v.u >> 16) & 1u)) >> 16;
    return (ushort)r;
}

// ============ convert W1, W2 to bf16 (one dispatch) ============
__global__ void k_convert(const float* __restrict__ W1, const float* __restrict__ W2,
                          ushort* __restrict__ W1b, ushort* __restrict__ W2b) {
    int i = blockIdx.x * 256 + threadIdx.x;      // 448 blocks -> 114688 threads
    if (i < Hz * GHz) W1b[i] = f2b(W1[i]);
    int j = i - Hz * GHz;
    if (j >= 0 && j < GHz * GHz) W2b[j] = f2b(W2[j]);
}

// ============ node gather: per (b,n) block; wave-synchronous gate; writes nf in bf16 ============
__global__ void k_node_gather(const float* __restrict__ lh, const int* __restrict__ submap,
                              const float* __restrict__ wr, const float* __restrict__ br,
                              ushort* __restrict__ nfb) {
    int n = blockIdx.x, b = blockIdx.y;
    int t = threadIdx.x;                  // 128 = 2 waves
    int lane = t & 63, wid = t >> 6;
    __shared__ int list[Sz];
    __shared__ int lcnt;
    __shared__ float partial[Hz];
    if (t == 0) lcnt = 0;
    __syncthreads();
    #pragma unroll
    for (int j = 0; j < 4; ++j) {
        int s = t + 128 * j;
        if (submap[b * Sz + s] == n) { int p = atomicAdd(&lcnt, 1); list[p] = s; }
    }
    __syncthreads();
    int cnt = lcnt;
    float brv = br[0];
    const float* wp = wr + lane * 12;
    float4 w0 = *(const float4*)&wp[0];
    float4 w1 = *(const float4*)&wp[4];
    float4 w2 = *(const float4*)&wp[8];
    float4 a0 = {0,0,0,0}, a1 = {0,0,0,0}, a2 = {0,0,0,0};
    for (int i = wid; i < cnt; i += 2) {
        const float* x = lh + (size_t)(b * Sz + list[i]) * Hz + lane * 12;
        float4 v0 = *(const float4*)&x[0];
        float4 v1 = *(const float4*)&x[4];
        float4 v2 = *(const float4*)&x[8];
        float p = v0.x*w0.x + v0.y*w0.y + v0.z*w0.z + v0.w*w0.w
                + v1.x*w1.x + v1.y*w1.y + v1.z*w1.z + v1.w*w1.w
                + v2.x*w2.x + v2.y*w2.y + v2.z*w2.z + v2.w*w2.w;
        #pragma unroll
        for (int off = 32; off > 0; off >>= 1) p += __shfl_down(p, off);
        float z = __shfl(p, 0) + brv;
        float g = 1.0f / (1.0f + __expf(-z));
        a0.x += g*v0.x; a0.y += g*v0.y; a0.z += g*v0.z; a0.w += g*v0.w;
        a1.x += g*v1.x; a1.y += g*v1.y; a1.z += g*v1.z; a1.w += g*v1.w;
        a2.x += g*v2.x; a2.y += g*v2.y; a2.z += g*v2.z; a2.w += g*v2.w;
    }
    if (wid == 1) {
        float* pp = partial + lane * 12;
        *(float4*)&pp[0] = a0; *(float4*)&pp[4] = a1; *(float4*)&pp[8] = a2;
    }
    __syncthreads();
    if (wid == 0) {
        float invc = 1.0f / fmaxf((float)cnt, 1.0f);
        const float* pp = partial + lane * 12;
        float4 p0 = *(const float4*)&pp[0];
        float4 p1 = *(const float4*)&pp[4];
        float4 p2 = *(const float4*)&pp[8];
        float o[12];
        o[0]=(a0.x+p0.x)*invc; o[1]=(a0.y+p0.y)*invc; o[2]=(a0.z+p0.z)*invc; o[3]=(a0.w+p0.w)*invc;
        o[4]=(a1.x+p1.x)*invc; o[5]=(a1.y+p1.y)*invc; o[6]=(a1.z+p1.z)*invc; o[7]=(a1.w+p1.w)*invc;
        o[8]=(a2.x+p2.x)*invc; o[9]=(a2.y+p2.y)*invc; o[10]=(a2.z+p2.z)*invc; o[11]=(a2.w+p2.w)*invc;
        unsigned* ob = (unsigned*)(nfb + (size_t)(b * Nz + n) * Hz + lane * 12);
        #pragma unroll
        for (int j = 0; j < 6; ++j)
            ob[j] = (unsigned)f2b(o[2*j]) | ((unsigned)f2b(o[2*j+1]) << 16);
    }
}

// ============ MFMA GEMM: C(BN x 128) = A_bf16(BN x K) @ W_bf16(K x 128), f32 out ============
// 128x128 tile, full K per block (no partials). 256 thr = 4 waves; wave w: rows [w*32, w*32+32).
// 16x16x32 bf16 MFMA. A-frag: A[m=lane&15][k=q*8+j]; B-frag: B[k=q*8+j][n=lane&15];
// C/D: row = q*4+reg, col = lane&15 (m89/m91-verified layouts).
#define ASP 40                 // As row stride in bf16 (80 B: 16B-aligned, banks spread)
#define BSP 48                 // Bt row stride in bf16 (96 B)
template <int K>
__global__ void k_gemm_mfma(const ushort* __restrict__ A, const ushort* __restrict__ W,
                            float* __restrict__ C) {
    __shared__ __align__(16) ushort As[128 * ASP];   // [row][k]   (32-k slice)
    __shared__ __align__(16) ushort Bt[128 * BSP];   // [n][k]     (32-k slice)
    int row_base = blockIdx.x * 128;
    int tid = threadIdx.x;                // 256
    int w = tid >> 6, lane = tid & 63;
    int q = lane >> 4, l16 = lane & 15;
    f32x4 acc[2][8];
    #pragma unroll
    for (int rt = 0; rt < 2; ++rt)
        #pragma unroll
        for (int ct = 0; ct < 8; ++ct) acc[rt][ct] = (f32x4){0,0,0,0};

    for (int k0 = 0; k0 < K; k0 += 32) {
        // A: 128 rows x 32 k = 512 x 16B segments, 2 per thread
        #pragma unroll
        for (int rep = 0; rep < 2; ++rep) {
            int idx = tid + 256 * rep;
            int r = idx >> 2, seg = idx & 3;
            *(uint4*)&As[r * ASP + seg * 8] =
                *(const uint4*)&A[(size_t)(row_base + r) * K + k0 + seg * 8];
        }
        // B: W[k][n] -> Bt[n][k]; thread owns 8 contiguous k for one n
        #pragma unroll
        for (int rep = 0; rep < 2; ++rep) {
            int idx = tid + 256 * rep;
            int n = idx & 127, kseg = idx >> 7;      // kseg 0..3
            ushort u[8];
            #pragma unroll
            for (int j = 0; j < 8; ++j)
                u[j] = W[(size_t)(k0 + kseg * 8 + j) * 128 + n];
            uint4 pk;
            pk.x = (unsigned)u[0] | ((unsigned)u[1] << 16);
            pk.y = (unsigned)u[2] | ((unsigned)u[3] << 16);
            pk.z = (unsigned)u[4] | ((unsigned)u[5] << 16);
            pk.w = (unsigned)u[6] | ((unsigned)u[7] << 16);
            *(uint4*)&Bt[n * BSP + kseg * 8] = pk;
        }
        __syncthreads();
        bf16x8 af[2];
        #pragma unroll
        for (int rt = 0; rt < 2; ++rt)
            af[rt] = *(const bf16x8*)&As[(w * 32 + rt * 16 + l16) * ASP + q * 8];
        #pragma unroll
        for (int ct = 0; ct < 8; ++ct) {
            bf16x8 bf = *(const bf16x8*)&Bt[(ct * 16 + l16) * BSP + q * 8];
            acc[0][ct] = __builtin_amdgcn_mfma_f32_16x16x32_bf16(af[0], bf, acc[0][ct], 0, 0, 0);
            acc[1][ct] = __builtin_amdgcn_mfma_f32_16x16x32_bf16(af[1], bf, acc[1][ct], 0, 0, 0);
        }
        __syncthreads();
    }
    #pragma unroll
    for (int rt = 0; rt < 2; ++rt)
        #pragma unroll
        for (int ct = 0; ct < 8; ++ct)
            #pragma unroll
            for (int r = 0; r < 4; ++r)
                C[(size_t)(row_base + w * 32 + rt * 16 + q * 4 + r) * 128 + ct * 16 + l16] =
                    acc[rt][ct][r];
}

// ============ edge gather per (b,dst), fused degree + bias + relu; optional bf16 output ============
template <bool OUT_BF>
__global__ void k_edge_gather(const float* __restrict__ h, const int* __restrict__ ei,
                              const float* __restrict__ bias,
                              float* __restrict__ outf, ushort* __restrict__ outb) {
    int d = blockIdx.x, b = blockIdx.y;
    int t = threadIdx.x;                  // 256
    __shared__ int list[Ez];
    __shared__ int lcnt;
    __shared__ int hist[Nz];
    __shared__ float accb[128];
    if (t == 0) lcnt = 0;
    if (t < Nz) hist[t] = 0;
    __syncthreads();
    const int* srcp = ei + b * 2 * Ez;
    const int* dstp = srcp + Ez;
    #pragma unroll
    for (int j = 0; j < 4; ++j) {
        int e = t + 256 * j;
        int dv = dstp[e];
        atomicAdd(&hist[dv], 1);
        if (dv == d) { int p = atomicAdd(&lcnt, 1); list[p] = e; }
    }
    __syncthreads();
    int cnt = lcnt;
    int col = t & 127, half = t >> 7;
    float dd = rsqrtf((float)hist[d] + 1.0f);
    float acc = (half == 0) ? h[(size_t)(b * Nz + d) * GHz + col] * dd * dd : 0.0f;  // self loop
    for (int i = half; i < cnt; i += 2) {
        int s = srcp[list[i]];
        float ds_ = rsqrtf((float)hist[s] + 1.0f);
        acc += h[(size_t)(b * Nz + s) * GHz + col] * (ds_ * dd);
    }
    if (half == 1) accb[col] = acc;
    __syncthreads();
    if (half == 0) {
        float v = fmaxf(acc + accb[col] + bias[col], 0.0f);
        if (OUT_BF) outb[(size_t)(b * Nz + d) * GHz + col] = f2b(v);
        else        outf[(size_t)(b * Nz + d) * GHz + col] = v;
    }
}

// ============ fused head: pooled = mean(x2[b]); h = relu([cls,pooled]@Wf1+bf1); out = h@Wf2+bf2 ============
__global__ void k_head(const float* __restrict__ lh, const float* __restrict__ x2,
                       const float* __restrict__ Wf1, const float* __restrict__ bf1,
                       const float* __restrict__ Wf2, const float* __restrict__ bf2,
                       float* __restrict__ out) {
    int b = blockIdx.x;
    int t = threadIdx.x;                  // 256
    __shared__ float in[Hz + GHz];        // 896
    __shared__ float buf[2][128];
    __shared__ float4 red4[4][64];
    __shared__ float hvec[FHz];
    __shared__ float red[256];
    for (int i = t; i < Hz; i += 256) in[i] = lh[(size_t)b * Sz * Hz + i];   // cls = s=0 row
    int col = t & 127, half = t >> 7;
    float s = 0.0f;
    for (int r = 0; r < 64; ++r)
        s += x2[(size_t)(b * Nz + half * 64 + r) * GHz + col];
    buf[half][col] = s;
    __syncthreads();
    if (t < 128) in[Hz + t] = (buf[0][t] + buf[1][t]) * (1.0f / Nz);
    __syncthreads();
    int c4 = t & 63, kc = t >> 6;
    float4 a = {0, 0, 0, 0};
    int k1 = kc * 224 + 224;
    for (int k = kc * 224; k < k1; ++k) {
        float iv = in[k];
        float4 w = *(const float4*)&Wf1[(size_t)k * FHz + c4 * 4];
        a.x += iv * w.x; a.y += iv * w.y; a.z += iv * w.z; a.w += iv * w.w;
    }
    red4[kc][c4] = a;
    __syncthreads();
    if (t < 64) {
        float4 s0 = red4[0][t], s1 = red4[1][t], s2 = red4[2][t], s3 = red4[3][t];
        float4 bb = *(const float4*)&bf1[t * 4];
        hvec[t * 4 + 0] = fmaxf(s0.x + s1.x + s2.x + s3.x + bb.x, 0.0f);
        hvec[t * 4 + 1] = fmaxf(s0.y + s1.y + s2.y + s3.y + bb.y, 0.0f);
        hvec[t * 4 + 2] = fmaxf(s0.z + s1.z + s2.z + s3.z + bb.z, 0.0f);
        hvec[t * 4 + 3] = fmaxf(s0.w + s1.w + s2.w + s3.w + bb.w, 0.0f);
    }
    __syncthreads();
    float hv = hvec[t];
    for (int l = 0; l < Lz; ++l) {
        red[t] = hv * Wf2[t * Lz + l];
        __syncthreads();
        for (int s2 = 128; s2 > 0; s2 >>= 1) {
            if (t < s2) red[t] += red[t + s2];
            __syncthreads();
        }
        if (t == 0) out[b * Lz + l] = red[0] + bf2[l];
        __syncthreads();
    }
}

extern "C" void kernel_launch(void* const* d_in, const int* in_sizes, int n_in,
                              void* d_out, int out_size, void* d_ws, size_t ws_size,
                              hipStream_t stream) {
    const float* lh     = (const float*)d_in[0];
    const int*   submap = (const int*)d_in[1];
    const int*   ei     = (const int*)d_in[2];
    const float* wr  = (const float*)d_in[4];
    const float* br  = (const float*)d_in[5];
    const float* W1  = (const float*)d_in[6];
    const float* b1  = (const float*)d_in[7];
    const float* W2  = (const float*)d_in[8];
    const float* b2  = (const float*)d_in[9];
    const float* Wf1 = (const float*)d_in[10];
    const float* bf1 = (const float*)d_in[11];
    const float* Wf2 = (const float*)d_in[12];
    const float* bf2 = (const float*)d_in[13];
    float* out = (float*)d_out;

    // ---- workspace layout (16B-aligned chunks) ----
    char* p = (char*)d_ws;
    ushort* nfb = (ushort*)p;            p += (size_t)BNz * Hz * 2;      // 12.6 MB bf16
    ushort* W1b = (ushort*)p;            p += (size_t)Hz * GHz * 2;      // 196 KB
    ushort* W2b = (ushort*)p;            p += (size_t)GHz * GHz * 2;     // 32 KB
    float*  h1  = (float*)p;             p += (size_t)BNz * GHz * 4;     // 4 MB
    ushort* x1b = (ushort*)p;            p += (size_t)BNz * GHz * 2;     // 2 MB
    float*  h2  = (float*)p;             p += (size_t)BNz * GHz * 4;     // 4 MB
    float*  x2  = (float*)p;             p += (size_t)BNz * GHz * 4;     // 4 MB

    // no memsets, no global atomics; every buffer fully written before read
    k_convert<<<(Hz * GHz + GHz * GHz) / 256, 256, 0, stream>>>(W1, W2, W1b, W2b);
    k_node_gather<<<dim3(Nz, Bz), 128, 0, stream>>>(lh, submap, wr, br, nfb);

    k_gemm_mfma<Hz><<<BNz / 128, 256, 0, stream>>>(nfb, W1b, h1);
    k_edge_gather<true><<<dim3(Nz, Bz), 256, 0, stream>>>(h1, ei, b1, nullptr, x1b);

    k_gemm_mfma<GHz><<<BNz / 128, 256, 0, stream>>>(x1b, W2b, h2);
    k_edge_gather<false><<<dim3(Nz, Bz), 256, 0, stream>>>(h2, ei, b2, x2, nullptr);

    k_head<<<Bz, 256, 0, stream>>>(lh, x2, Wf1, bf1, Wf2, bf2, out);
}